// Round 8
// baseline (104.010 us; speedup 1.0000x reference)
//
#include <hip/hip_runtime.h>
#include <hip/hip_bf16.h>
#include <math.h>

// SupConLoss, B=4096 V=2 D=128, N=8192.
// loss = (1/N) [ sum_i log(sum_{j!=i} exp(n_i.n_j/T)) - 2*sum_b spos_b ]
// Round 8: BARRIER-FREE main kernel. B-operand MFMA fragments are loaded
// directly from global (same 16B-per-lane pattern as A fragments) — no LDS,
// no __syncthreads in the hot loop, AITER-style load<->MFMA interleave with
// compiler vmcnt. Wave = 64 rows x 32-col steps (2:1 MFMA:load).
// R2-R7 evidence: the 2-barrier LDS K-loop pinned main at ~32us with all
// pipes <10% busy; barrier drain was the structural cost.

constexpr int   Bsz   = 4096;
constexpr int   Nrows = 8192;
constexpr int   Dd    = 128;
constexpr float TEMPf = 0.07f;
constexpr float EPSN  = 1e-8f;
constexpr float SCALE = 1.4426950408889634f / 0.07f;  // log2(e)/T
constexpr float LN2   = 0.6931471805599453f;

constexpr int CHUNKS     = 32;                 // col chunks (grid.x)
constexpr int CHUNK_COLS = Nrows / CHUNKS;     // 256
constexpr int CTS        = CHUNK_COLS / 32;    // 8 col-steps of 32
constexpr int ROWS_BLK   = 256;                // rows per block (4 waves x 64)
constexpr int PREPBLKS   = Bsz / 4;            // 1024

typedef __attribute__((ext_vector_type(8)))  short bf16x8;   // 8 bf16 = 4 VGPRs
typedef __attribute__((ext_vector_type(16))) float floatx16; // MFMA 32x32 C/D

// ws layout (bytes):
//   0x000000  nB   bf16[8192][128]   2 MB
//   0x200000  nA   bf16[8192][128]   2 MB  (pre-scaled by SCALE)
//   0x400000  partial f32[32][8192]  1 MB
//   0x500000  sposPart f32[1024]     4 KB
constexpr size_t OFF_NA   = 0x200000;
constexpr size_t OFF_PART = 0x400000;
constexpr size_t OFF_SPOS = 0x500000;

// ------------- prep: normalize both views + per-block spos sums ----------------
__global__ void prep_k(const float* __restrict__ f,
                       __hip_bfloat16* __restrict__ nB,
                       __hip_bfloat16* __restrict__ nA,
                       float* __restrict__ sposPart,
                       float* __restrict__ out) {
    __shared__ float sred[4];
    int tid  = threadIdx.x;
    int wid  = tid >> 6;
    int lane = tid & 63;
    int b    = blockIdx.x * 4 + wid;
    if (blockIdx.x == 0 && tid == 0) out[0] = 0.f;   // final_k accumulates

    const float* s0 = f + (size_t)(b * 2) * Dd;       // features[b, 0, :]
    float2 x = *(const float2*)(s0 + lane * 2);       // view 0
    float2 y = *(const float2*)(s0 + Dd + lane * 2);  // view 1
    float ss0 = x.x * x.x + x.y * x.y;
    float ss1 = y.x * y.x + y.y * y.y;
    float dt  = x.x * y.x + x.y * y.y;
    #pragma unroll
    for (int off = 32; off; off >>= 1) {
        ss0 += __shfl_xor(ss0, off);
        ss1 += __shfl_xor(ss1, off);
        dt  += __shfl_xor(dt,  off);
    }
    float inv0 = 1.0f / fmaxf(sqrtf(ss0), EPSN);
    float inv1 = 1.0f / fmaxf(sqrtf(ss1), EPSN);
    __hip_bfloat162 h;
    h.x = __float2bfloat16(x.x * inv0);
    h.y = __float2bfloat16(x.y * inv0);
    *(__hip_bfloat162*)(nB + (size_t)b * Dd + lane * 2) = h;
    h.x = __float2bfloat16(x.x * inv0 * SCALE);
    h.y = __float2bfloat16(x.y * inv0 * SCALE);
    *(__hip_bfloat162*)(nA + (size_t)b * Dd + lane * 2) = h;
    h.x = __float2bfloat16(y.x * inv1);
    h.y = __float2bfloat16(y.y * inv1);
    *(__hip_bfloat162*)(nB + (size_t)(Bsz + b) * Dd + lane * 2) = h;
    h.x = __float2bfloat16(y.x * inv1 * SCALE);
    h.y = __float2bfloat16(y.y * inv1 * SCALE);
    *(__hip_bfloat162*)(nA + (size_t)(Bsz + b) * Dd + lane * 2) = h;

    if (lane == 0) sred[wid] = dt * inv0 * inv1 / TEMPf;
    __syncthreads();
    if (tid == 0) sposPart[blockIdx.x] = sred[0] + sred[1] + sred[2] + sred[3];
}

// ------------- main: barrier-free fused nA·nB^T -> exp2 -> row sums ------------
// Grid (32 chunks, 32 row-groups), 256 thr = 4 waves. Wave w: rows
// by*256 + w*64 (two 32-row halves), cols = 256-col chunk in 8 steps of 32.
// A fragments (64 VGPRs) and B fragments are DIRECT global loads:
// B frag for lane = nB[col = cb32 + lo][16 B at kc*32 + hi*16] — identical
// pattern to A. All 4 waves stream the same B cols -> high L1 hit rate.
__global__ __launch_bounds__(256, 3)
void main_k(const __hip_bfloat16* __restrict__ nA, const __hip_bfloat16* __restrict__ nB,
            float* __restrict__ partial) {
    const int tid  = threadIdx.x;
    const int wid  = tid >> 6;
    const int lane = tid & 63;
    const int lo   = lane & 31;
    const int hi   = lane >> 5;
    const int rbase = blockIdx.y * ROWS_BLK + wid * 64;  // wave's 64 rows
    const int cbase = blockIdx.x * CHUNK_COLS;

    // A fragments: row = rbase + s*32 + lo, k-bytes = kc*32 + hi*16  (64 VGPRs)
    bf16x8 afrag[2][8];
    #pragma unroll
    for (int s = 0; s < 2; s++) {
        const char* rowp = (const char*)nA + (size_t)(rbase + s * 32 + lo) * 256 + hi * 16;
        #pragma unroll
        for (int kc = 0; kc < 8; kc++)
            afrag[s][kc] = *(const bf16x8*)(rowp + kc * 32);
    }

    float sums[2][16];
    #pragma unroll
    for (int s = 0; s < 2; s++)
        #pragma unroll
        for (int r = 0; r < 16; r++) sums[s][r] = 0.f;

    floatx16 zero = {};
    // per-lane B base: column cbase+lo, k-offset hi*16
    const char* bp = (const char*)nB + (size_t)(cbase + lo) * 256 + hi * 16;

    #pragma unroll 1   // rolled: full unroll would hoist 64 loads -> spill (R5)
    for (int ct = 0; ct < CTS; ct++) {
        const char* bcol = bp + (size_t)ct * 32 * 256;   // advance 32 cols
        floatx16 acc0 = zero, acc1 = zero;
        #pragma unroll
        for (int kc = 0; kc < 8; kc++) {
            bf16x8 bf = *(const bf16x8*)(bcol + kc * 32);
            acc0 = __builtin_amdgcn_mfma_f32_32x32x16_bf16(afrag[0][kc], bf, acc0, 0, 0, 0);
            acc1 = __builtin_amdgcn_mfma_f32_32x32x16_bf16(afrag[1][kc], bf, acc1, 0, 0, 0);
        }

        // epilogue: exp2 (SCALE pre-folded into A), diagonal mask, row-sum acc
        const int cb32 = cbase + ct * 32;
        #pragma unroll
        for (int s = 0; s < 2; s++) {
            const floatx16& acc = s ? acc1 : acc0;
            bool dt_hit = (cb32 == rbase + s * 32);   // wave-uniform
            #pragma unroll
            for (int r = 0; r < 16; r++) {
                float e = __builtin_amdgcn_exp2f(acc[r]);
                // C/D layout (m74/m101): col=lo, row_local=(r&3)+8*(r>>2)+4*hi
                if (dt_hit && lo == ((r & 3) + 8 * (r >> 2) + 4 * hi)) e = 0.f;
                sums[s][r] += e;
            }
        }
    }

    // row sums: reduce across 32 col-lanes; write partial[chunk][row]
    #pragma unroll
    for (int s = 0; s < 2; s++)
        #pragma unroll
        for (int r = 0; r < 16; r++) {
            float v = sums[s][r];
            #pragma unroll
            for (int off = 1; off < 32; off <<= 1) v += __shfl_xor(v, off);
            sums[s][r] = v;
        }
    if (lo == 0) {
        float* prow = partial + (size_t)blockIdx.x * Nrows;
        #pragma unroll
        for (int s = 0; s < 2; s++)
            #pragma unroll
            for (int r = 0; r < 16; r++) {
                int grow = rbase + s * 32 + (r & 3) + 8 * (r >> 2) + 4 * hi;
                prow[grow] = sums[s][r];
            }
    }
}

// ------------- finalize: 32 blocks; atomicAdd the scalar -----------------------
__global__ __launch_bounds__(256)
void final_k(const float* __restrict__ partial, const float* __restrict__ sposPart,
             float* __restrict__ out) {
    __shared__ float red[4];
    int tid = threadIdx.x;
    int r = blockIdx.x * 256 + tid;
    float se = 0.f;
    #pragma unroll
    for (int p = 0; p < CHUNKS; p++) se += partial[(size_t)p * Nrows + r];
    float acc = __builtin_amdgcn_logf(se) * LN2;   // v_log_f32 is log2
    if (tid < 32) acc -= 2.f * sposPart[blockIdx.x * 32 + tid];
    #pragma unroll
    for (int off = 32; off; off >>= 1) acc += __shfl_xor(acc, off);
    if ((tid & 63) == 0) red[tid >> 6] = acc;
    __syncthreads();
    if (tid == 0)
        atomicAdd(out, (red[0] + red[1] + red[2] + red[3]) / (float)Nrows);
}

extern "C" void kernel_launch(void* const* d_in, const int* in_sizes, int n_in,
                              void* d_out, int out_size, void* d_ws, size_t ws_size,
                              hipStream_t stream) {
    const float* f = (const float*)d_in[0];
    char* ws = (char*)d_ws;
    __hip_bfloat16* nB = (__hip_bfloat16*)ws;
    __hip_bfloat16* nA = (__hip_bfloat16*)(ws + OFF_NA);
    float* partial     = (float*)(ws + OFF_PART);
    float* sposPart    = (float*)(ws + OFF_SPOS);

    prep_k<<<PREPBLKS, 256, 0, stream>>>(f, nB, nA, sposPart, (float*)d_out);
    dim3 grid(CHUNKS, Nrows / ROWS_BLK);
    main_k<<<grid, 256, 0, stream>>>(nA, nB, partial);
    final_k<<<Nrows / 256, 256, 0, stream>>>(partial, sposPart, (float*)d_out);
}

// Round 9
// 85.368 us; speedup vs baseline: 1.2184x; 1.2184x over previous
//
#include <hip/hip_runtime.h>
#include <hip/hip_bf16.h>
#include <math.h>

// SupConLoss, B=4096 V=2 D=128, N=8192.
// loss = (1/N) [ sum_i log(sum_{j!=i} exp(n_i.n_j/T)) - 2*sum_b spos_b ]
// Round 9: barrier-free main + FRAGMENT-MAJOR n layout.
// R8 evidence: direct global fragment loads with row-major n are a 256-B-stride
// gather (32 cache lines per load instr) -> 48us. Fix: prep writes n in MFMA
// fragment order nF[g=row/32][kc][lane]*16B so every A/B fragment load is a
// fully coalesced 1KB global_load_dwordx4. One buffer serves both operands
// (A-frag and B-frag patterns are identical); SCALE applied in epilogue.

constexpr int   Bsz   = 4096;
constexpr int   Nrows = 8192;
constexpr int   Dd    = 128;
constexpr float TEMPf = 0.07f;
constexpr float EPSN  = 1e-8f;
constexpr float SCALE = 1.4426950408889634f / 0.07f;  // log2(e)/T
constexpr float LN2   = 0.6931471805599453f;

constexpr int CHUNKS     = 32;                 // col chunks (grid.x)
constexpr int CHUNK_COLS = Nrows / CHUNKS;     // 256
constexpr int CTS        = CHUNK_COLS / 32;    // 8 col-steps of 32
constexpr int ROWS_BLK   = 256;                // rows per block (4 waves x 64)
constexpr int PREPBLKS   = Bsz / 4;            // 1024

typedef __attribute__((ext_vector_type(8)))  short bf16x8;   // 8 bf16 = 4 VGPRs
typedef __attribute__((ext_vector_type(16))) float floatx16; // MFMA 32x32 C/D

// Fragment-major layout: row r = g*32 + lo holds its 256 B as 16 pieces
// (kc=0..7, hi=0..1), piece addr = g*8192 + kc*1024 + hi*512 + lo*16.
// A wave's fragment load (g, kc) = base + g*8192 + kc*1024 + lane*16 (1 KB).

// ws layout (bytes):
//   0x000000  nF   fragment-major bf16 n   2 MB
//   0x200000  partial f32[32][8192]        1 MB
//   0x300000  sposPart f32[1024]           4 KB
constexpr size_t OFF_PART = 0x200000;
constexpr size_t OFF_SPOS = 0x300000;

// ------------- prep: normalize both views -> nF + per-block spos sums ----------
__global__ void prep_k(const float* __restrict__ f,
                       char* __restrict__ nF,
                       float* __restrict__ sposPart,
                       float* __restrict__ out) {
    __shared__ float sred[4];
    int tid  = threadIdx.x;
    int wid  = tid >> 6;
    int lane = tid & 63;
    int b    = blockIdx.x * 4 + wid;
    if (blockIdx.x == 0 && tid == 0) out[0] = 0.f;   // final_k accumulates

    const float* s0 = f + (size_t)(b * 2) * Dd;       // features[b, 0, :]
    float2 x = *(const float2*)(s0 + lane * 2);       // view 0
    float2 y = *(const float2*)(s0 + Dd + lane * 2);  // view 1
    float ss0 = x.x * x.x + x.y * x.y;
    float ss1 = y.x * y.x + y.y * y.y;
    float dt  = x.x * y.x + x.y * y.y;
    #pragma unroll
    for (int off = 32; off; off >>= 1) {
        ss0 += __shfl_xor(ss0, off);
        ss1 += __shfl_xor(ss1, off);
        dt  += __shfl_xor(dt,  off);
    }
    float inv0 = 1.0f / fmaxf(sqrtf(ss0), EPSN);
    float inv1 = 1.0f / fmaxf(sqrtf(ss1), EPSN);

    // lane holds k = 2*lane, 2*lane+1  ->  piece (kc = lane>>3, hi = (lane>>2)&1),
    // byte offset within piece = (lane&3)*4
    int kc  = lane >> 3;
    int hi2 = (lane >> 2) & 1;
    int rem = (lane & 3) * 4;
    size_t poff = (size_t)kc * 1024 + hi2 * 512 + rem;

    __hip_bfloat162 h;
    // view 0 -> row b
    h.x = __float2bfloat16(x.x * inv0);
    h.y = __float2bfloat16(x.y * inv0);
    *(__hip_bfloat162*)(nF + (size_t)(b >> 5) * 8192 + (b & 31) * 16 + poff) = h;
    // view 1 -> row Bsz + b
    int r1 = Bsz + b;
    h.x = __float2bfloat16(y.x * inv1);
    h.y = __float2bfloat16(y.y * inv1);
    *(__hip_bfloat162*)(nF + (size_t)(r1 >> 5) * 8192 + (r1 & 31) * 16 + poff) = h;

    if (lane == 0) sred[wid] = dt * inv0 * inv1 / TEMPf;
    __syncthreads();
    if (tid == 0) sposPart[blockIdx.x] = sred[0] + sred[1] + sred[2] + sred[3];
}

// ------------- main: barrier-free fused n·n^T -> exp2 -> row sums --------------
// Grid (32 chunks, 32 row-groups), 256 thr = 4 waves, no LDS, no barriers.
// Wave: 64 rows (two 32-row halves) x 256 cols in 8 steps of 32.
// Every fragment load is a coalesced 1 KB global_load_dwordx4 from nF (L2-hot).
__global__ __launch_bounds__(256, 3)
void main_k(const char* __restrict__ nF, float* __restrict__ partial) {
    const int tid  = threadIdx.x;
    const int wid  = tid >> 6;
    const int lane = tid & 63;
    const int lo   = lane & 31;
    const int hi   = lane >> 5;
    const int rbase = blockIdx.y * ROWS_BLK + wid * 64;  // wave's 64 rows
    const int cbase = blockIdx.x * CHUNK_COLS;           // 256-aligned

    // A fragments: two 32-row groups, 8 coalesced loads each (64 VGPRs)
    bf16x8 afrag[2][8];
    #pragma unroll
    for (int s = 0; s < 2; s++) {
        const char* ag = nF + (size_t)((rbase + s * 32) >> 5) * 8192 + lane * 16;
        #pragma unroll
        for (int kc = 0; kc < 8; kc++)
            afrag[s][kc] = *(const bf16x8*)(ag + kc * 1024);
    }

    float sums[2][16];
    #pragma unroll
    for (int s = 0; s < 2; s++)
        #pragma unroll
        for (int r = 0; r < 16; r++) sums[s][r] = 0.f;

    floatx16 zero = {};
    const char* bbase = nF + (size_t)(cbase >> 5) * 8192 + lane * 16;

    #pragma unroll 1   // rolled: unrolling hoists loads -> spill (R5 lesson)
    for (int ct = 0; ct < CTS; ct++) {
        const char* bg = bbase + (size_t)ct * 8192;
        floatx16 acc0 = zero, acc1 = zero;
        #pragma unroll
        for (int kc = 0; kc < 8; kc++) {
            bf16x8 bf = *(const bf16x8*)(bg + kc * 1024);   // coalesced 1 KB
            acc0 = __builtin_amdgcn_mfma_f32_32x32x16_bf16(afrag[0][kc], bf, acc0, 0, 0, 0);
            acc1 = __builtin_amdgcn_mfma_f32_32x32x16_bf16(afrag[1][kc], bf, acc1, 0, 0, 0);
        }

        // epilogue: e = exp2(s * SCALE), diagonal mask, row-sum accumulate
        const int cb32 = cbase + ct * 32;
        #pragma unroll
        for (int s = 0; s < 2; s++) {
            const floatx16& acc = s ? acc1 : acc0;
            bool dt_hit = (cb32 == rbase + s * 32);   // wave-uniform
            #pragma unroll
            for (int r = 0; r < 16; r++) {
                float e = __builtin_amdgcn_exp2f(acc[r] * SCALE);
                // C/D layout (m74/m101): col=lo, row_local=(r&3)+8*(r>>2)+4*hi
                if (dt_hit && lo == ((r & 3) + 8 * (r >> 2) + 4 * hi)) e = 0.f;
                sums[s][r] += e;
            }
        }
    }

    // row sums: reduce across 32 col-lanes; write partial[chunk][row]
    #pragma unroll
    for (int s = 0; s < 2; s++)
        #pragma unroll
        for (int r = 0; r < 16; r++) {
            float v = sums[s][r];
            #pragma unroll
            for (int off = 1; off < 32; off <<= 1) v += __shfl_xor(v, off);
            sums[s][r] = v;
        }
    if (lo == 0) {
        float* prow = partial + (size_t)blockIdx.x * Nrows;
        #pragma unroll
        for (int s = 0; s < 2; s++)
            #pragma unroll
            for (int r = 0; r < 16; r++) {
                int grow = rbase + s * 32 + (r & 3) + 8 * (r >> 2) + 4 * hi;
                prow[grow] = sums[s][r];
            }
    }
}

// ------------- finalize: 32 blocks; atomicAdd the scalar -----------------------
__global__ __launch_bounds__(256)
void final_k(const float* __restrict__ partial, const float* __restrict__ sposPart,
             float* __restrict__ out) {
    __shared__ float red[4];
    int tid = threadIdx.x;
    int r = blockIdx.x * 256 + tid;
    float se = 0.f;
    #pragma unroll
    for (int p = 0; p < CHUNKS; p++) se += partial[(size_t)p * Nrows + r];
    float acc = __builtin_amdgcn_logf(se) * LN2;   // v_log_f32 is log2
    if (tid < 32) acc -= 2.f * sposPart[blockIdx.x * 32 + tid];
    #pragma unroll
    for (int off = 32; off; off >>= 1) acc += __shfl_xor(acc, off);
    if ((tid & 63) == 0) red[tid >> 6] = acc;
    __syncthreads();
    if (tid == 0)
        atomicAdd(out, (red[0] + red[1] + red[2] + red[3]) / (float)Nrows);
}

extern "C" void kernel_launch(void* const* d_in, const int* in_sizes, int n_in,
                              void* d_out, int out_size, void* d_ws, size_t ws_size,
                              hipStream_t stream) {
    const float* f = (const float*)d_in[0];
    char* ws = (char*)d_ws;
    char* nF        = ws;
    float* partial  = (float*)(ws + OFF_PART);
    float* sposPart = (float*)(ws + OFF_SPOS);

    prep_k<<<PREPBLKS, 256, 0, stream>>>(f, nF, sposPart, (float*)d_out);
    dim3 grid(CHUNKS, Nrows / ROWS_BLK);
    main_k<<<grid, 256, 0, stream>>>(nF, partial);
    final_k<<<Nrows / 256, 256, 0, stream>>>(partial, sposPart, (float*)d_out);
}